// Round 4
// baseline (167.150 us; speedup 1.0000x reference)
//
#include <hip/hip_runtime.h>

typedef float f32x4 __attribute__((ext_vector_type(4)));
typedef short short8 __attribute__((ext_vector_type(8)));
typedef unsigned short ushort_t;
typedef unsigned int uint_t;

// (B,T,D,H) = (64, 32, 256, 4); DIMS = [1024, 512, 256, 128, 64, 4]
constexpr int O_CAM   = 0;
constexpr int O_ROT   = 64;
constexpr int O_TRANS = 320;
constexpr int O_PLANE = 512;
constexpr int O_VALID = 66048;

// Workspace layout (byte offsets)
constexpr size_t B_G1   = 0;         // f32 [64][256]
constexpr size_t B_G2   = 65536;     // f32 [64][256]
constexpr size_t B_G    = 131072;    // f32 [4][64][512]
constexpr size_t B_ACC  = 655360;    // f32 [64][8]
constexpr size_t B_ABF  = 657408;    // bf16 [4][64][32][512]  (A' = A + G)
constexpr size_t B_CBF  = 9046016;   // bf16 [4][64][32][512]
constexpr size_t B_BT1  = 17434624;  // bf16 frag [4][16ks][16nt][64][8]
constexpr size_t B_BT2  = 18483200;  // bf16 frag [4][8][8][64][8]
constexpr size_t B_BT3  = 18745344;  // bf16 frag [4][4][4][64][8]
constexpr size_t B_BT0  = 18810880;  // bf16 frag [8hc][8ks][32nt][64][8]  (W0 a|c)
constexpr size_t B_BT0G = 20908032;  // bf16 frag [4h][16ks][32nt][64][8]  (W0 g1|g2)
// end = 23005184 bytes (~23 MB)

__device__ __forceinline__ ushort_t f2bf(float f) {
    uint_t u = __float_as_uint(f);
    return (ushort_t)((u + 0x7FFFu + ((u >> 16) & 1u)) >> 16);
}

__device__ __forceinline__ uint_t bfadd2_relu(uint_t a, uint_t c) {
    float lo = __uint_as_float(a << 16) + __uint_as_float(c << 16);
    float hi = __uint_as_float(a & 0xffff0000u) + __uint_as_float(c & 0xffff0000u);
    lo = fmaxf(lo, 0.f);
    hi = fmaxf(hi, 0.f);
    return (uint_t)f2bf(lo) | ((uint_t)f2bf(hi) << 16);
}

// ================= K-prep: all weight reshuffles + group means + acc zero =================
// grid x: [0,1344) w1/w2/w3 frags | [1344,3392) W0 a/c frags | [3392,5440) W0 g frags
//         [5440,5504) group means | 5504 acc zero
__global__ __launch_bounds__(64) void k_prep(
    const float* __restrict__ emb, const int* __restrict__ np_,
    const float* __restrict__ w0, const float* __restrict__ w1,
    const float* __restrict__ w2, const float* __restrict__ w3,
    ushort_t* __restrict__ bt1, ushort_t* __restrict__ bt2, ushort_t* __restrict__ bt3,
    ushort_t* __restrict__ bt0, ushort_t* __restrict__ bt0g,
    float* __restrict__ g1, float* __restrict__ g2, float* __restrict__ accz)
{
    const int l = threadIdx.x;
    int c = blockIdx.x;
    if (c < 1344) {
        const float* w; ushort_t* dst; int K, N;
        if (c < 1024)      {           w = w1; dst = bt1 + (size_t)c*512; K = 512; N = 256; }
        else if (c < 1280) { c -= 1024; w = w2; dst = bt2 + (size_t)c*512; K = 256; N = 128; }
        else               { c -= 1280; w = w3; dst = bt3 + (size_t)c*512; K = 128; N = 64;  }
        const int NT = N/16, KS_NT = (K/32)*NT;
        const int h = c / KS_NT, rem = c % KS_NT, ks = rem / NT, nt = rem % NT;
        const int n = nt*16 + (l & 15);
        const int d0 = ks*32 + ((l >> 4) << 3);
        short8 o;
        #pragma unroll
        for (int j = 0; j < 8; ++j)
            o[j] = (short)f2bf(w[((size_t)(h*K + d0 + j))*N + n]);
        *(short8*)(dst + (size_t)l*8) = o;
    } else if (c < 3392) {
        c -= 1344;
        const int nt = c & 31, ks = (c >> 5) & 7, hc = c >> 8;
        const int h = hc >> 1, isC = hc & 1;
        const int n = nt*16 + (l & 15);
        const int d0 = isC*256 + ks*32 + ((l >> 4) << 3);
        short8 o;
        #pragma unroll
        for (int j = 0; j < 8; ++j)
            o[j] = (short)f2bf(w0[((size_t)h*1024 + d0 + j)*512 + n]);
        *(short8*)(bt0 + ((size_t)c*64 + l)*8) = o;
    } else if (c < 5440) {
        c -= 3392;
        const int h = c >> 9, ks = (c >> 5) & 15, nt = c & 31;
        const int n = nt*16 + (l & 15);
        const int d0 = 512 + ks*32 + ((l >> 4) << 3);
        short8 o;
        #pragma unroll
        for (int j = 0; j < 8; ++j)
            o[j] = (short)f2bf(w0[((size_t)h*1024 + d0 + j)*512 + n]);
        *(short8*)(bt0g + ((size_t)c*64 + l)*8) = o;
    } else if (c < 5504) {
        const int b = c - 5440;
        const int n0 = np_[2*b], n1 = np_[2*b+1];
        const float* e = emb + (size_t)b*8192;
        #pragma unroll
        for (int dd = 0; dd < 4; ++dd) {
            const int d = l + 64*dd;
            float a1 = 0.f, a2 = 0.f;
            for (int t = 0; t < 32; ++t) {
                float v = e[t*256 + d];
                if (t < n0) a1 += v;
                else if (t < n0 + n1) a2 += v;
            }
            g1[b*256 + d] = a1 / n0;
            g2[b*256 + d] = a2 / n1;
        }
    } else {
        #pragma unroll
        for (int i = 0; i < 8; ++i) accz[l*8 + i] = 0.f;
    }
}

// ================= K-Gm: G = (g1|g2) @ W0g + b0 via MFMA (M=64 over b) =================
// grid 8 = (h*2 + nhalf), 256 threads
__global__ __launch_bounds__(256) void k_Gm(
    const float* __restrict__ g1, const float* __restrict__ g2,
    const ushort_t* __restrict__ bt0g, const float* __restrict__ b0,
    float* __restrict__ G)
{
    const int h = blockIdx.x >> 1, nh = blockIdx.x & 1;
    const int tid = threadIdx.x;
    const int l = tid & 63, w = tid >> 6;
    const int lrow = l & 15, lko = l >> 4;

    __shared__ __align__(16) char xg[65536];   // bf16 [64][512], stride 1024B, swizzled

    for (int i = 0; i < 16; ++i) {
        const int flat = i*256 + tid;          // [64 rows][64 k-octets]
        const int row = flat >> 6, ko = flat & 63;
        const int k = ko*8;
        const float* src = (k < 256) ? (g1 + row*256 + k) : (g2 + row*256 + (k - 256));
        const float4 v0 = *(const float4*)(src);
        const float4 v1 = *(const float4*)(src + 4);
        uint4 p;
        p.x = (uint_t)f2bf(v0.x) | ((uint_t)f2bf(v0.y) << 16);
        p.y = (uint_t)f2bf(v0.z) | ((uint_t)f2bf(v0.w) << 16);
        p.z = (uint_t)f2bf(v1.x) | ((uint_t)f2bf(v1.y) << 16);
        p.w = (uint_t)f2bf(v1.z) | ((uint_t)f2bf(v1.w) << 16);
        *(uint4*)(xg + ((row*1024 + ko*16) ^ ((row & 7) << 4))) = p;
    }
    __syncthreads();

    f32x4 acc[4][4];
    #pragma unroll
    for (int mt = 0; mt < 4; ++mt)
        #pragma unroll
        for (int nt = 0; nt < 4; ++nt) acc[mt][nt] = (f32x4){0.f,0.f,0.f,0.f};

    const ushort_t* bp = bt0g + (size_t)h*(16*32*512) + (size_t)(nh*16 + w*4)*512 + (size_t)l*8;
    short8 bb[2][4];
    #pragma unroll
    for (int nt = 0; nt < 4; ++nt) bb[0][nt] = *(const short8*)(bp + (size_t)nt*512);
    #pragma unroll
    for (int ks = 0; ks < 16; ++ks) {
        if (ks < 15) {
            #pragma unroll
            for (int nt = 0; nt < 4; ++nt)
                bb[(ks+1)&1][nt] = *(const short8*)(bp + (size_t)(ks+1)*16384 + (size_t)nt*512);
        }
        short8 a[4];
        #pragma unroll
        for (int mt = 0; mt < 4; ++mt)
            a[mt] = *(const short8*)(xg + (((mt*16 + lrow)*1024 + ks*64 + lko*16) ^ ((lrow & 7) << 4)));
        #pragma unroll
        for (int nt = 0; nt < 4; ++nt)
            #pragma unroll
            for (int mt = 0; mt < 4; ++mt)
                acc[mt][nt] = __builtin_amdgcn_mfma_f32_16x16x32_bf16(a[mt], bb[ks&1][nt], acc[mt][nt], 0, 0, 0);
    }

    #pragma unroll
    for (int nt = 0; nt < 4; ++nt) {
        const int col = nh*256 + w*64 + nt*16 + lrow;
        const float bias = b0[h*512 + col];
        #pragma unroll
        for (int mt = 0; mt < 4; ++mt)
            #pragma unroll
            for (int r = 0; r < 4; ++r) {
                const int brow = mt*16 + lko*4 + r;
                G[((size_t)h*64 + brow)*512 + col] = acc[mt][nt][r] + bias;
            }
    }
}

// ================= K-AC: A' and C via MFMA (M=32, K=256, N=512) =================
__global__ __launch_bounds__(256) void k_AC(
    const float* __restrict__ emb, const ushort_t* __restrict__ bt0,
    const float* __restrict__ Gbuf,
    ushort_t* __restrict__ Abf, ushort_t* __restrict__ Cbf)
{
    const int b = blockIdx.x, hc = blockIdx.y;
    const int h = hc >> 1, isC = hc & 1;
    const int tid = threadIdx.x;
    const int l = tid & 63, w4 = tid >> 6;
    const int lrow = l & 15, lko = l >> 4;

    __shared__ __align__(16) char es[16384];   // bf16 [32][256], stride 512B, swizzled

    {
        const float* eb = emb + (size_t)b*8192;
        #pragma unroll
        for (int j = 0; j < 16; ++j) {
            const int flat = j*256 + tid;
            const int row = flat >> 7, cp = flat & 127;
            const float2 v = *(const float2*)(eb + row*256 + cp*2);
            const uint_t p = (uint_t)f2bf(v.x) | ((uint_t)f2bf(v.y) << 16);
            const int byte = (row*512 + cp*4) ^ ((row & 7) << 4);
            *(uint_t*)(es + byte) = p;
        }
    }
    __syncthreads();

    f32x4 acc[2][8];
    #pragma unroll
    for (int mt = 0; mt < 2; ++mt)
        #pragma unroll
        for (int nt = 0; nt < 8; ++nt) acc[mt][nt] = (f32x4){0.f,0.f,0.f,0.f};

    const ushort_t* bp = bt0 + (size_t)hc*131072 + (size_t)(w4*8)*512 + (size_t)l*8;
    short8 bb[2][8];
    #pragma unroll
    for (int nt = 0; nt < 8; ++nt) bb[0][nt] = *(const short8*)(bp + nt*512);
    #pragma unroll
    for (int ks = 0; ks < 8; ++ks) {
        if (ks < 7) {
            #pragma unroll
            for (int nt = 0; nt < 8; ++nt)
                bb[(ks+1)&1][nt] = *(const short8*)(bp + (size_t)(ks+1)*16384 + nt*512);
        }
        const int o = (lrow*512 + ks*64 + lko*16) ^ ((lrow & 7) << 4);
        const short8 a0 = *(const short8*)(es + o);
        const short8 a1 = *(const short8*)(es + o + 8192);
        #pragma unroll
        for (int nt = 0; nt < 8; ++nt) {
            acc[0][nt] = __builtin_amdgcn_mfma_f32_16x16x32_bf16(a0, bb[ks&1][nt], acc[0][nt], 0, 0, 0);
            acc[1][nt] = __builtin_amdgcn_mfma_f32_16x16x32_bf16(a1, bb[ks&1][nt], acc[1][nt], 0, 0, 0);
        }
    }

    ushort_t* dst = (isC ? Cbf : Abf) + (size_t)(h*64 + b)*32*512;
    const float* Gr = Gbuf + (size_t)(h*64 + b)*512;
    #pragma unroll
    for (int nt = 0; nt < 8; ++nt) {
        const int col = (w4*8 + nt)*16 + lrow;
        const float g = isC ? 0.f : Gr[col];
        #pragma unroll
        for (int mt = 0; mt < 2; ++mt)
            #pragma unroll
            for (int r = 0; r < 4; ++r) {
                const int row = mt*16 + lko*4 + r;
                dst[row*512 + col] = f2bf(acc[mt][nt][r] + g);
            }
    }
}

// ================= K-MLP: persistent-weight fused MLP =================
// grid 640: x<256: h=3, b=x>>2, octet=x&3 (8 t per block, M=32 = all s)
//           x>=256: y=x-256, h=y>>7, b=(y&127)>>1, chunk=y&1
//                   (t-pairs p=chunk,chunk+2,.. while 2p<n0; M=32 = 2t x 16 s-window)
__global__ __launch_bounds__(512, 2) void k_mlp(
    const ushort_t* __restrict__ Abf, const ushort_t* __restrict__ Cbf,
    const ushort_t* __restrict__ bt1, const ushort_t* __restrict__ bt2, const ushort_t* __restrict__ bt3,
    const float* __restrict__ b1, const float* __restrict__ b2, const float* __restrict__ b3,
    const float* __restrict__ w4, const float* __restrict__ b4,
    const int* __restrict__ np_, float* __restrict__ out, float* __restrict__ accbuf)
{
    __shared__ __align__(16) char smem[115712];
    // 0:      X0 bf16 [32][512] (32KB)  | reused: X2 @0 (8KB), X3 f32 @8192 (8KB), X4 @16384
    // 32768:  X1 bf16 [32][256] (16KB)
    // 49152:  W2 frags (64KB)
    // 114688: w4 f32 (1KB)
    char* X0 = smem;
    char* X1 = smem + 32768;
    char* W2L = smem + 49152;
    float* w4L = (float*)(smem + 114688);

    const int x = blockIdx.x;
    const bool isH3 = (x < 256);
    int h, b, oct = 0, chunk = 0;
    if (isH3) { h = 3; b = x >> 2; oct = x & 3; }
    else { const int y = x - 256; h = y >> 7; const int r = y & 127; b = r >> 1; chunk = r & 1; }

    int n0 = 0, n1 = 0;
    if (!isH3) {
        n0 = np_[2*b]; n1 = np_[2*b+1];
        if (chunk == 1 && n0 <= 2) return;   // no pairs for this chunk
    }

    const int tid = threadIdx.x;
    const int l = tid & 63, w = tid >> 6;
    const int lrow = l & 15, lko = l >> 4;
    const size_t hb = (size_t)(h*64 + b);

    // ---- phase 0: stage weights ----
    {
        const uint4* src = (const uint4*)(bt2 + (size_t)h*32768);
        uint4* dst = (uint4*)W2L;
        #pragma unroll
        for (int i = 0; i < 8; ++i) dst[i*512 + tid] = src[i*512 + tid];
    }
    if (tid < 256) w4L[tid] = w4[h*256 + tid];

    short8 F1[16][2];
    {
        const ushort_t* bp = bt1 + (size_t)h*131072 + (size_t)(w*2)*512 + (size_t)l*8;
        #pragma unroll
        for (int ks = 0; ks < 16; ++ks) {
            F1[ks][0] = *(const short8*)(bp + (size_t)ks*8192);
            F1[ks][1] = *(const short8*)(bp + (size_t)ks*8192 + 512);
        }
    }
    short8 F3[4];
    {
        const ushort_t* bp = bt3 + (size_t)h*8192 + (size_t)(w & 3)*512 + (size_t)l*8;
        #pragma unroll
        for (int ks = 0; ks < 4; ++ks) F3[ks] = *(const short8*)(bp + (size_t)ks*2048);
    }
    float bias1_0 = b1[h*256 + w*32 + lrow];
    float bias1_1 = b1[h*256 + w*32 + 16 + lrow];
    float bias2   = b2[h*128 + w*16 + lrow];
    float bias3   = b3[h*64 + (w & 3)*16 + lrow];
    float bias4   = (tid < 128) ? b4[h*4 + (tid & 3)] : 0.f;
    const int mhalf = w >> 2;

    for (int it = 0; ; ++it) {
        int t0, t1 = -1;
        if (isH3) {
            if (it >= 8) break;
            t0 = oct*8 + it;
        } else {
            const int p = chunk + 2*it;
            if (2*p >= n0) break;
            t0 = 2*p; t1 = 2*p + 1;
        }

        __syncthreads();   // protect X0 region from previous iteration's readers

        // ---- X0 = relu(A'[t] + C[s]) ----
        {
            #pragma unroll
            for (int cc = 0; cc < 4; ++cc) {
                const int flat = cc*512 + tid;
                const int row = flat >> 6, ko = flat & 63;
                int crow, trow;
                if (isH3) { crow = row; trow = t0; }
                else { crow = n0 + (row & 15); trow = (row < 16) ? t0 : t1; }
                const uint4 ca = ((const uint4*)(Cbf + (hb*32 + crow)*512))[ko];
                const uint4 aa = ((const uint4*)(Abf + (hb*32 + trow)*512))[ko];
                uint4 p;
                p.x = bfadd2_relu(aa.x, ca.x);
                p.y = bfadd2_relu(aa.y, ca.y);
                p.z = bfadd2_relu(aa.z, ca.z);
                p.w = bfadd2_relu(aa.w, ca.w);
                *(uint4*)(X0 + ((row*1024 + ko*16) ^ ((row & 7) << 4))) = p;
            }
        }
        __syncthreads();

        // ---- layer1: 512 -> 256 (W1 in registers) ----
        f32x4 acc1[2][2];
        acc1[0][0] = (f32x4){0.f,0.f,0.f,0.f}; acc1[0][1] = (f32x4){0.f,0.f,0.f,0.f};
        acc1[1][0] = (f32x4){0.f,0.f,0.f,0.f}; acc1[1][1] = (f32x4){0.f,0.f,0.f,0.f};
        #pragma unroll
        for (int ks = 0; ks < 16; ++ks) {
            const int o = (lrow*1024 + ks*64 + lko*16) ^ ((lrow & 7) << 4);
            const short8 a0 = *(const short8*)(X0 + o);
            const short8 a1 = *(const short8*)(X0 + o + 16384);
            acc1[0][0] = __builtin_amdgcn_mfma_f32_16x16x32_bf16(a0, F1[ks][0], acc1[0][0], 0, 0, 0);
            acc1[1][0] = __builtin_amdgcn_mfma_f32_16x16x32_bf16(a1, F1[ks][0], acc1[1][0], 0, 0, 0);
            acc1[0][1] = __builtin_amdgcn_mfma_f32_16x16x32_bf16(a0, F1[ks][1], acc1[0][1], 0, 0, 0);
            acc1[1][1] = __builtin_amdgcn_mfma_f32_16x16x32_bf16(a1, F1[ks][1], acc1[1][1], 0, 0, 0);
        }
        #pragma unroll
        for (int j = 0; j < 2; ++j) {
            const int col = w*32 + j*16 + lrow;
            const float bias = (j == 0) ? bias1_0 : bias1_1;
            #pragma unroll
            for (int mt = 0; mt < 2; ++mt)
                #pragma unroll
                for (int r = 0; r < 4; ++r) {
                    const int row = mt*16 + lko*4 + r;
                    *(ushort_t*)(X1 + ((row*512 + col*2) ^ ((row & 7) << 4))) =
                        f2bf(fmaxf(acc1[mt][j][r] + bias, 0.f));
                }
        }
        __syncthreads();

        // ---- layer2: 256 -> 128 (W2 in LDS); X2 overlays X0 ----
        f32x4 acc2[2];
        acc2[0] = (f32x4){0.f,0.f,0.f,0.f};
        acc2[1] = (f32x4){0.f,0.f,0.f,0.f};
        #pragma unroll
        for (int ks = 0; ks < 8; ++ks) {
            const int o = (lrow*512 + ks*64 + lko*16) ^ ((lrow & 7) << 4);
            const short8 a0 = *(const short8*)(X1 + o);
            const short8 a1 = *(const short8*)(X1 + o + 8192);
            const short8 bf = *(const short8*)(W2L + (ks*8 + w)*1024 + l*16);
            acc2[0] = __builtin_amdgcn_mfma_f32_16x16x32_bf16(a0, bf, acc2[0], 0, 0, 0);
            acc2[1] = __builtin_amdgcn_mfma_f32_16x16x32_bf16(a1, bf, acc2[1], 0, 0, 0);
        }
        {
            const int col = w*16 + lrow;
            #pragma unroll
            for (int mt = 0; mt < 2; ++mt)
                #pragma unroll
                for (int r = 0; r < 4; ++r) {
                    const int row = mt*16 + lko*4 + r;
                    *(ushort_t*)(X0 + ((row*256 + col*2) ^ ((row & 7) << 4))) =
                        f2bf(fmaxf(acc2[mt][r] + bias2, 0.f));
                }
        }
        __syncthreads();

        // ---- layer3: 128 -> 64 (W3 in registers); wave = (ntile=w&3, mhalf=w>>2) ----
        f32x4 acc3 = (f32x4){0.f,0.f,0.f,0.f};
        #pragma unroll
        for (int ks = 0; ks < 4; ++ks) {
            const int arow = mhalf*16 + lrow;
            const int o = (arow*256 + ks*64 + lko*16) ^ ((lrow & 7) << 4);
            const short8 a0 = *(const short8*)(X0 + o);
            acc3 = __builtin_amdgcn_mfma_f32_16x16x32_bf16(a0, F3[ks], acc3, 0, 0, 0);
        }
        float* X3 = (float*)(smem + 8192);
        {
            const int col = (w & 3)*16 + lrow;
            #pragma unroll
            for (int r = 0; r < 4; ++r)
                X3[(mhalf*16 + lko*4 + r)*64 + col] = fmaxf(acc3[r] + bias3, 0.f);
        }
        __syncthreads();

        // ---- layer4: 64 -> 4 (VALU, 128 threads, bank-staggered) ----
        float* X4 = (float*)(smem + 16384);
        if (tid < 128) {
            const int row = tid >> 2, o = tid & 3;
            float a = bias4;
            #pragma unroll
            for (int dd = 0; dd < 16; ++dd) {
                const int dbase = ((row + dd) & 15) * 4;
                const float4 xv = *(const float4*)(X3 + row*64 + dbase);
                a = fmaf(xv.x, w4L[(dbase + 0)*4 + o], a);
                a = fmaf(xv.y, w4L[(dbase + 1)*4 + o], a);
                a = fmaf(xv.z, w4L[(dbase + 2)*4 + o], a);
                a = fmaf(xv.w, w4L[(dbase + 3)*4 + o], a);
            }
            X4[row*4 + o] = a;
        }
        __syncthreads();

        // ---- outputs ----
        if (isH3) {
            if (tid < 32)
                out[O_PLANE + b*1024 + t0*32 + tid] = 1.f / (1.f + expf(-X4[tid*4]));
        } else {
            const int nj = (h == 0) ? 1 : ((h == 1) ? 4 : 3);
            if (tid < 128) {
                const int j = tid >> 5, r = tid & 31;
                if (j < nj) {
                    const int rr = r & 15;
                    const bool tvalid = (r < 16) || (t1 < n0);
                    float v = (rr < n1 && tvalid) ? X4[r*4 + j] : 0.f;
                    #pragma unroll
                    for (int off = 16; off > 0; off >>= 1) v += __shfl_down(v, off, 32);
                    if (r == 0) {
                        const int slot = (h == 0) ? 0 : ((h == 1) ? 1 + j : 5 + j);
                        atomicAdd(&accbuf[b*8 + slot], v);
                    }
                }
            }
        }
    }
}

// ================= K-final: valid mask + finalize reductions =================
__global__ __launch_bounds__(1024) void k_final(
    const int* __restrict__ np_, const float* __restrict__ acc, float* __restrict__ out)
{
    const int b = blockIdx.x, tid = threadIdx.x;
    const int n0 = np_[2*b], n1 = np_[2*b+1];
    const int t = tid >> 5, s = tid & 31;
    out[O_VALID + b*1024 + tid] = (t < n0 && s >= n0 && s < n0 + n1) ? 1.f : 0.f;
    const float pf = (float)(n0 * n1);
    if (tid == 0) {
        out[O_CAM + b] = 1.f / (1.f + expf(-acc[b*8] / pf));
    } else if (tid <= 4) {
        out[O_ROT + b*4 + (tid - 1)] = acc[b*8 + tid] / pf;
    } else if (tid <= 7) {
        out[O_TRANS + b*3 + (tid - 5)] = acc[b*8 + tid] / pf;
    }
}

extern "C" void kernel_launch(void* const* d_in, const int* in_sizes, int n_in,
                              void* d_out, int out_size, void* d_ws, size_t ws_size,
                              hipStream_t stream) {
    (void)in_sizes; (void)n_in; (void)out_size; (void)ws_size;
    const float* emb = (const float*)d_in[0];
    const int*   np_ = (const int*)d_in[1];
    const float* w0  = (const float*)d_in[2];
    const float* b0  = (const float*)d_in[3];
    const float* w1  = (const float*)d_in[4];
    const float* b1  = (const float*)d_in[5];
    const float* w2  = (const float*)d_in[6];
    const float* b2  = (const float*)d_in[7];
    const float* w3  = (const float*)d_in[8];
    const float* b3  = (const float*)d_in[9];
    const float* w4  = (const float*)d_in[10];
    const float* b4  = (const float*)d_in[11];

    char* W = (char*)d_ws;
    float* out = (float*)d_out;
    float*    g1   = (float*)(W + B_G1);
    float*    g2   = (float*)(W + B_G2);
    float*    G    = (float*)(W + B_G);
    float*    acc  = (float*)(W + B_ACC);
    ushort_t* Abf  = (ushort_t*)(W + B_ABF);
    ushort_t* Cbf  = (ushort_t*)(W + B_CBF);
    ushort_t* bt1  = (ushort_t*)(W + B_BT1);
    ushort_t* bt2  = (ushort_t*)(W + B_BT2);
    ushort_t* bt3  = (ushort_t*)(W + B_BT3);
    ushort_t* bt0  = (ushort_t*)(W + B_BT0);
    ushort_t* bt0g = (ushort_t*)(W + B_BT0G);

    k_prep<<<5505, 64, 0, stream>>>(emb, np_, w0, w1, w2, w3,
                                    bt1, bt2, bt3, bt0, bt0g, g1, g2, acc);
    k_Gm<<<8, 256, 0, stream>>>(g1, g2, bt0g, b0, G);
    k_AC<<<dim3(64, 8), 256, 0, stream>>>(emb, bt0, G, Abf, Cbf);
    k_mlp<<<640, 512, 0, stream>>>(Abf, Cbf, bt1, bt2, bt3,
                                   b1, b2, b3, w4, b4, np_, out, acc);
    k_final<<<64, 1024, 0, stream>>>(np_, acc, out);
}